// Round 4
// baseline (204.265 us; speedup 1.0000x reference)
//
#include <hip/hip_runtime.h>

#define TLEN 512
#define HID  64

typedef _Float16 half8 __attribute__((ext_vector_type(8)));
typedef float    f32x4 __attribute__((ext_vector_type(4)));

__device__ __forceinline__ float rcp_fast(float x) { return __builtin_amdgcn_rcpf(x); }
__device__ __forceinline__ float exp2_fast(float x) {
#if __has_builtin(__builtin_amdgcn_exp2f)
    return __builtin_amdgcn_exp2f(x);
#else
    float r; asm("v_exp_f32 %0, %1" : "=v"(r) : "v"(x)); return r;
#endif
}

// R15 = R14 (159 us) + pre-gate-in-accumulator.
// The pre-gate xt*wih+bias is a valid C[m][n] (row=gate/unit, col=batch), so
// it rides in C_in of a chained MFMA pair instead of being added on the VALU:
//   t = mfma(a_hi, b1, mfma(a_lo, b0, C_pre))
// Removes the 8 merge-adds and halves the selects (8 cndmask -> 4): bundle
// VALU 35 -> 26 ops. Costs chain depth 2 (two independent chains, ~+17 cyc
// skeleton) + 4 extra pre-fmas. State kept as S = 2K*c (kills the z-mul).
// Trans floor stays 5 exp2 + 2 rcp (algebraic minimum for this cell).
__global__ __launch_bounds__(512) __attribute__((amdgpu_waves_per_eu(2, 2)))
void lstm_mfma8(const float* __restrict__ x,
                const float* __restrict__ W_ih,
                const float* __restrict__ W_hh,
                const float* __restrict__ b_ih,
                const float* __restrict__ b_hh,
                const float* __restrict__ W_d,
                const float* __restrict__ b_d,
                float* __restrict__ out) {
    __shared__ __align__(16) float    xs[8][516];     // 8 x rows
    __shared__ __align__(16) _Float16 hbuf[2][8][80]; // ping-pong h, pad 80

    const int tid = threadIdx.x;
    const int L   = tid & 63;
    const int w   = tid >> 6;        // wave 0..7, owns units [8w, 8w+8)
    const int r0  = blockIdx.x * 8;

    // ---- stage x rows (float4) ----
    for (int i = tid; i < 8 * 128; i += 512) {
        const int r = i >> 7, t4 = (i & 127) * 4;
        *(float4*)&xs[r][t4] = *(const float4*)&x[(size_t)(r0 + r) * TLEN + t4];
    }
    // ---- zero both h buffers (h0 = 0) ----
    for (int i = tid; i < 2 * 8 * 80; i += 512)
        ((_Float16*)hbuf)[i] = (_Float16)0.0f;

    const float K  = 1.44269504f;    // log2 e
    const float K2 = 2.0f * K;

    // ---- resident A-frags: A[m][k], m=L&15, k=32q+(L>>4)*8+i ----
    // tile tt -> unit 8w+4tt+(m>>2), gate m&3 (i,f,g,o)
    // Gate scale folded into A: s = -K (i,f,o), +2K (g).
    half8 af[2][2];
    {
        const int m = L & 15;
        const int g = m & 3;
        const int kb = (L >> 4) * 8;
        const float sg = (g == 2) ? K2 : -K;
#pragma unroll
        for (int tt = 0; tt < 2; ++tt) {
            const int uu = 8 * w + 4 * tt + (m >> 2);
            const float* row = &W_hh[(size_t)(g * HID + uu) * HID];
#pragma unroll
            for (int q = 0; q < 2; ++q) {
                const float* p = row + 32 * q + kb;
                half8 hf;
#pragma unroll
                for (int i = 0; i < 8; ++i) hf[i] = (_Float16)(sg * p[i]);
                af[tt][q] = hf;
            }
        }
    }

    // ---- lane role: col c, batch b (8 real rows), tile-select dup, unit u ----
    const int c   = L & 15;
    const int b   = c & 7;
    const int dup = (c >> 3) & 1;
    const int rg  = L >> 4;
    // lane's act: unit u = 8w + 4*dup + rg (gates j=0..3 are its 4 C-regs of
    // tile 'dup'); exactly one activation per lane, 64 distinct (b,u).

    // per-tile pre-gate params, pre-scaled into exp2 domain (both tiles:
    // C_in must be valid for the whole 16x16 tile, not just selected lanes)
    float wihT[2][4], biasT[2][4];
#pragma unroll
    for (int tt = 0; tt < 2; ++tt) {
        const int ut = 8 * w + 4 * tt + rg;
#pragma unroll
        for (int g = 0; g < 4; ++g) {
            const float s = (g == 2) ? K2 : -K;
            wihT[tt][g]  = s * W_ih[g * HID + ut];
            biasT[tt][g] = s * (b_ih[g * HID + ut] + b_hh[g * HID + ut]);
        }
    }

    const float* xrow = &xs[b][0];
    const int koff = rg * 8;
    const _Float16* h0r = &hbuf[0][b][0];
    _Float16*       h0w = &hbuf[0][0][0];
    const _Float16* h1r = &hbuf[1][b][0];
    _Float16*       h1w = &hbuf[1][0][0];
    const int widx = b * 80 + (8 * w + 4 * dup + rg); // write offset
    float S = 0.0f;                  // state: S = 2K * c

    __syncthreads();

    auto step = [&](const _Float16* hin, _Float16* hout, float xt) {
        // pre-gates ride in the MFMA accumulator (8 fma, both tiles)
        f32x4 c0, c1;
#pragma unroll
        for (int g = 0; g < 4; ++g) {
            c0[g] = fmaf(xt, wihT[0][g], biasT[0][g]);
            c1[g] = fmaf(xt, wihT[1][g], biasT[1][g]);
        }

        half8 b0 = *(const half8*)(hin + koff);
        half8 b1 = *(const half8*)(hin + koff + 32);

        // two independent chains of depth 2; acc carries the pre-gate
        f32x4 t0 = __builtin_amdgcn_mfma_f32_16x16x32_f16(af[0][0], b0, c0, 0, 0, 0);
        f32x4 t1 = __builtin_amdgcn_mfma_f32_16x16x32_f16(af[1][0], b0, c1, 0, 0, 0);
        t0 = __builtin_amdgcn_mfma_f32_16x16x32_f16(af[0][1], b1, t0, 0, 0, 0);
        t1 = __builtin_amdgcn_mfma_f32_16x16x32_f16(af[1][1], b1, t1, 0, 0, 0);

        // single 4-wide select (was 8 cndmask + 8 adds)
        f32x4 dS;
#pragma unroll
        for (int g = 0; g < 4; ++g) dS[g] = dup ? t1[g] : t0[g];

        // args already scaled: -K*a for i,f,o; +2K*a for g
        const float ei = exp2_fast(dS[0]);
        const float ef = exp2_fast(dS[1]);
        const float eg = exp2_fast(dS[2]);
        const float eo = exp2_fast(dS[3]);

        // merged-ratio cell on S = 2K*c: 2 rcp total
        const float A1  = 1.0f + ei;
        const float B1  = 1.0f + eg;
        const float E1  = 1.0f + ef;
        const float C1K = fmaf(eg, K2, -K2);     // 2K*(eg-1)
        const float Pig = A1 * B1;               // (1+ei)(1+eg)
        const float Dde = E1 * Pig;              // common denominator
        const float CEK = C1K * E1;
        const float num = fmaf(S, Pig, CEK);
        S = num * rcp_fast(Dde);                 // S' = 2K*(gf*c + gi*gg)
        const float ec = exp2_fast(S);
        const float F1 = 1.0f + eo;
        const float G1 = 1.0f + ec;
        const float H1 = ec - 1.0f;
        const float hv = H1 * rcp_fast(F1 * G1); // go * tanh(c')
        hout[widx] = (_Float16)hv;  // one write per lane, 64 unique (b,u)
    };

    for (int t = 0; t < TLEN; t += 4) {
        // x register-blocking: one b128 read covers 4 steps (16B-aligned)
        const float4 xq = *(const float4*)&xrow[t];
        step(h0r, h1w, xq.x);
        __syncthreads();
        step(h1r, h0w, xq.y);
        __syncthreads();
        step(h0r, h1w, xq.z);
        __syncthreads();
        step(h1r, h0w, xq.w);
        __syncthreads();
    }

    // ---- epilogue: wave w reduces batch row w (final h in hbuf[0]) ----
    float pv = (float)hbuf[0][w][L] * W_d[L];
#pragma unroll
    for (int off = 32; off > 0; off >>= 1)
        pv += __shfl_xor(pv, off, 64);
    if (L == 0)
        out[r0 + w] = pv + b_d[0];
}

extern "C" void kernel_launch(void* const* d_in, const int* in_sizes, int n_in,
                              void* d_out, int out_size, void* d_ws, size_t ws_size,
                              hipStream_t stream) {
    const float* x    = (const float*)d_in[0];
    const float* W_ih = (const float*)d_in[1];
    const float* W_hh = (const float*)d_in[2];
    const float* b_ih = (const float*)d_in[3];
    const float* b_hh = (const float*)d_in[4];
    const float* W_d  = (const float*)d_in[5];
    const float* b_d  = (const float*)d_in[6];
    float* out = (float*)d_out;

    dim3 grid(256);    // 2048 / 8 batch rows per block -> 1 block/CU
    dim3 block(512);   // 8 waves = 2/SIMD (R11 shape, best measured)
    lstm_mfma8<<<grid, block, 0, stream>>>(x, W_ih, W_hh, b_ih, b_hh, W_d, b_d, out);
}